// Round 6
// baseline (100.392 us; speedup 1.0000x reference)
//
#include <hip/hip_runtime.h>
#include <stdint.h>

// GINConv1d: B=4, N=8192, K=16, C_IN=C_OUT=128
//
// R5 post-mortem: occupancy knobs on the fused structure are exhausted (equal
// outstanding-loads/CU at occ2x32 vs occ4x16; block doubling only adds fixed
// cost). R6 restructures via linearity:
//   h@W^T = (1+eps)(x@W^T) + sum_j (x_j@W^T)
// kernel1: dense GEMM y = x@W^T (no gather), W split hi/lo bf16 (2 MFMAs) so y
//          is near-fp32 accurate; y stored bf16 (2 MiB/XCD, L2-resident),
//          XCD-batch pinned to the consumer XCD pair.
// kernel2: pure streaming gather-sum on y: no LDS, no barrier, no W, no MFMA;
//          16xshort8 prefetch + own + bias + relu + nt stores. Natural high
//          occupancy (~110 VGPR, 8 blocks/CU).
#define BATCH   4
#define NNODE   8192
#define KNBR    16
#define CIN     128
#define COUT    128
#define MB1     32          // gemm rows/block -> 1024 blocks
#define MB2     16          // gather nodes/block -> 2048 blocks
#define THREADS 256
#define HS_STRIDE 136       // shorts per LDS row: 128 + 8 pad

#define XELEM   (BATCH * NNODE * CIN)          // 4194304 elements

typedef __attribute__((ext_vector_type(8))) short short8;   // 8 bf16 (MFMA A/B frag)
typedef __attribute__((ext_vector_type(4))) float f32x4;
typedef __attribute__((ext_vector_type(4))) int   i32x4;

__device__ __forceinline__ short bf16_rne(float f) {
    union { float f; uint32_t u; } v; v.f = f;
    return (short)((v.u + 0x7FFFu + ((v.u >> 16) & 1u)) >> 16);  // round-to-nearest-even
}
__device__ __forceinline__ float bf16_f32(short s) {
    union { uint32_t u; float f; } v; v.u = ((uint32_t)(uint16_t)s) << 16;
    return v.f;
}

// ---------------- kernel1: y = x @ W^T, hi/lo-split W, y -> bf16 -------------------
__global__ __launch_bounds__(THREADS)
void gemm_xw(const float* __restrict__ x,      // [B,N,CIN] fp32
             const float* __restrict__ W,      // [COUT,CIN] fp32
             ushort*      __restrict__ yb)     // [B,N,COUT] bf16 out
{
    __shared__ __align__(16) short h_s[MB1 * HS_STRIDE];

    const int tid = threadIdx.x;
    // Same XCD-batch pinning as the gather kernel: y rows for batch b are
    // produced (and left dirty in L2) on XCDs {2b,2b+1}, where they're consumed.
    const int i   = blockIdx.x;            // 0..1023
    const int xcd = i & 7;
    const int sub = i >> 3;                // 0..127
    const int b   = xcd >> 1;              // batch 0..3
    const int wbi = ((xcd & 1) << 7) | sub;// 0..255 within batch
    const int n0  = wbi * MB1;
    const int row0 = b * NNODE + n0;

    // Phase A: x fp32 -> bf16 LDS tile (one-shot x read: nontemporal)
    {
        const int r  = tid >> 3;           // 0..31
        const int q  = tid & 7;            // 0..7
        const int c0 = q * 16;
        const float* xs = x + (size_t)(row0 + r) * CIN + c0;
        f32x4 v0 = __builtin_nontemporal_load((const f32x4*)xs);
        f32x4 v1 = __builtin_nontemporal_load((const f32x4*)(xs + 4));
        f32x4 v2 = __builtin_nontemporal_load((const f32x4*)(xs + 8));
        f32x4 v3 = __builtin_nontemporal_load((const f32x4*)(xs + 12));
        short8 s0, s1;
        s0[0]=bf16_rne(v0[0]); s0[1]=bf16_rne(v0[1]); s0[2]=bf16_rne(v0[2]); s0[3]=bf16_rne(v0[3]);
        s0[4]=bf16_rne(v1[0]); s0[5]=bf16_rne(v1[1]); s0[6]=bf16_rne(v1[2]); s0[7]=bf16_rne(v1[3]);
        s1[0]=bf16_rne(v2[0]); s1[1]=bf16_rne(v2[1]); s1[2]=bf16_rne(v2[2]); s1[3]=bf16_rne(v2[3]);
        s1[4]=bf16_rne(v3[0]); s1[5]=bf16_rne(v3[1]); s1[6]=bf16_rne(v3[2]); s1[7]=bf16_rne(v3[3]);
        short* hp = h_s + r * HS_STRIDE + c0;
        *(short8*)hp       = s0;
        *(short8*)(hp + 8) = s1;
    }

    // W -> hi/lo bf16 fragments: W = H + L with |W-(H+L)| ~ 2^-18|W|, so the
    // two-MFMA GEMM (x*H + x*L) is near-fp32 accurate in y.
    const int wave = tid >> 6;
    const int lane = tid & 63;
    const int l16  = lane & 15;
    const int lq   = lane >> 4;            // quad 0..3

    short8 bH[2][4], bL[2][4];
    #pragma unroll
    for (int t = 0; t < 2; ++t) {
        const float* wp = W + (size_t)(wave * 32 + t * 16 + l16) * CIN;
        #pragma unroll
        for (int kb = 0; kb < 4; ++kb) {
            const float* wq = wp + kb * 32 + lq * 8;
            f32x4 f0 = *(const f32x4*)(wq);
            f32x4 f1 = *(const f32x4*)(wq + 4);
            short8 h, l;
            #pragma unroll
            for (int e = 0; e < 4; ++e) {
                short h0 = bf16_rne(f0[e]);
                short h1 = bf16_rne(f1[e]);
                h[e]   = h0; l[e]   = bf16_rne(f0[e] - bf16_f32(h0));
                h[4+e] = h1; l[4+e] = bf16_rne(f1[e] - bf16_f32(h1));
            }
            bH[t][kb] = h; bL[t][kb] = l;
        }
    }

    __syncthreads();

    // Phase B: MFMA, y -> bf16 store (regular stores: keep y dirty in L2)
    ushort* ybb = yb + (size_t)row0 * COUT;
    #pragma unroll
    for (int rt = 0; rt < MB1 / 16; ++rt) {
        const short* ap = h_s + (rt * 16 + l16) * HS_STRIDE + lq * 8;
        short8 a[4];
        #pragma unroll
        for (int kb = 0; kb < 4; ++kb)
            a[kb] = *(const short8*)(ap + kb * 32);

        #pragma unroll
        for (int t = 0; t < 2; ++t) {
            f32x4 acc = { 0.f, 0.f, 0.f, 0.f };
            #pragma unroll
            for (int kb = 0; kb < 4; ++kb) {
                acc = __builtin_amdgcn_mfma_f32_16x16x32_bf16(a[kb], bH[t][kb], acc, 0, 0, 0);
                acc = __builtin_amdgcn_mfma_f32_16x16x32_bf16(a[kb], bL[t][kb], acc, 0, 0, 0);
            }
            const int col = wave * 32 + t * 16 + l16;
            #pragma unroll
            for (int ii = 0; ii < 4; ++ii) {
                const int row = rt * 16 + lq * 4 + ii;   // C/D: row = quad*4 + reg
                ybb[(size_t)row * COUT + col] = (ushort)bf16_rne(acc[ii]);
            }
        }
    }
}

// ---------------- kernel2: out = relu((1+eps)*y + sum_j y_j + bias) ----------------
// Pure streaming gather: no LDS, no barriers, no MFMA. launch_bounds(256,3)
// caps VGPR at 170 (usage ~110, no spill) -> 4+ waves/SIMD natural occupancy.
__global__ __launch_bounds__(THREADS, 3)
void gin_gather(const ushort* __restrict__ yb,    // [B,N,COUT] bf16
                const int*    __restrict__ eidx,  // [2,B,N,K] int32; plane 0
                const float*  __restrict__ bias,  // [COUT]
                const float*  __restrict__ epsp,  // [1]
                float*        __restrict__ out)   // [B,N,COUT] fp32
{
    const int tid = threadIdx.x;
    const int i   = blockIdx.x;            // 0..2047
    const int xcd = i & 7;
    const int sub = i >> 3;                // 0..255
    const int b   = xcd >> 1;              // batch pinned to XCD pair {2b,2b+1}
    const int wbi = ((xcd & 1) << 8) | sub;// 0..511 within batch
    const int n0  = wbi * MB2;

    const int r  = tid >> 4;               // node within block, 0..15
    const int q  = tid & 15;               // channel slice, 8 ch each
    const int n  = n0 + r;
    const int c0 = q * 8;

    const int* ip = eidx + ((size_t)b * NNODE + n) * KNBR;   // plane 0
    int js[KNBR];
    #pragma unroll
    for (int p = 0; p < 4; ++p) {
        i32x4 jv = __builtin_nontemporal_load((const i32x4*)(ip + p * 4));
        js[p*4+0]=jv.x; js[p*4+1]=jv.y; js[p*4+2]=jv.z; js[p*4+3]=jv.w;
    }

    const ushort* ybb = yb + (size_t)b * NNODE * CIN;
    short8 own = *(const short8*)(ybb + (size_t)n * CIN + c0);

    // All 16 neighbor slices in flight before any accumulation.
    short8 t[KNBR];
    #pragma unroll
    for (int k = 0; k < KNBR; ++k)
        t[k] = *(const short8*)(ybb + (size_t)js[k] * CIN + c0);
    __builtin_amdgcn_sched_barrier(0);

    const float eps1 = 1.0f + epsp[0];
    f32x4 b0 = *(const f32x4*)(bias + c0);
    f32x4 b1 = *(const f32x4*)(bias + c0 + 4);

    float acc[8];
    #pragma unroll
    for (int e = 0; e < 4; ++e) {
        acc[e]     = eps1 * bf16_f32(own[e])     + b0[e];
        acc[4 + e] = eps1 * bf16_f32(own[4 + e]) + b1[e];
    }
    #pragma unroll
    for (int k = 0; k < KNBR; ++k) {
        #pragma unroll
        for (int e = 0; e < 8; ++e) acc[e] += bf16_f32(t[k][e]);
    }

    f32x4 o0, o1;
    #pragma unroll
    for (int e = 0; e < 4; ++e) {
        o0[e] = acc[e]     > 0.f ? acc[e]     : 0.f;
        o1[e] = acc[4 + e] > 0.f ? acc[4 + e] : 0.f;
    }
    float* op = out + ((size_t)b * NNODE + n) * COUT + c0;
    __builtin_nontemporal_store(o0, (f32x4*)op);         // don't evict the y tile
    __builtin_nontemporal_store(o1, (f32x4*)(op + 4));
}

// ---------------- fallback (no workspace): R4's fp32 fused path --------------------
__global__ __launch_bounds__(THREADS, 2)
void gin_fallback(const float* __restrict__ x, const int* __restrict__ eidx,
                  const float* __restrict__ W, const float* __restrict__ bias,
                  const float* __restrict__ epsp, float* __restrict__ out)
{
    __shared__ __align__(16) short h_s[MB1 * HS_STRIDE];
    const int tid = threadIdx.x;
    const int i   = blockIdx.x;
    const int xcd = i & 7, sub = i >> 3;
    const int b   = xcd >> 1;
    const int wbi = ((xcd & 1) << 7) | sub;
    const int n0  = wbi * MB1;
    const int row0 = b * NNODE + n0;
    const float eps1 = 1.0f + epsp[0];
    {
        const int r = tid >> 3, q = tid & 7, n = n0 + r, c0 = q * 16;
        const int* ip = eidx + ((size_t)b * NNODE + n) * KNBR;
        int js[KNBR];
        #pragma unroll
        for (int p = 0; p < 4; ++p) {
            i32x4 jv = *(const i32x4*)(ip + p * 4);
            js[p*4+0]=jv.x; js[p*4+1]=jv.y; js[p*4+2]=jv.z; js[p*4+3]=jv.w;
        }
        float acc[16];
        const float* xbb = x + (size_t)b * NNODE * CIN;
        const float* xs  = xbb + (size_t)n * CIN + c0;
        #pragma unroll
        for (int p = 0; p < 4; ++p) {
            f32x4 v = *(const f32x4*)(xs + p * 4);
            acc[p*4+0]=eps1*v[0]; acc[p*4+1]=eps1*v[1]; acc[p*4+2]=eps1*v[2]; acc[p*4+3]=eps1*v[3];
        }
        #pragma unroll
        for (int k = 0; k < KNBR; ++k) {
            const float* xn = xbb + (size_t)js[k] * CIN + c0;
            #pragma unroll
            for (int p = 0; p < 4; ++p) {
                f32x4 v = *(const f32x4*)(xn + p * 4);
                acc[p*4+0]+=v[0]; acc[p*4+1]+=v[1]; acc[p*4+2]+=v[2]; acc[p*4+3]+=v[3];
            }
        }
        short* hp = h_s + r * HS_STRIDE + c0;
        #pragma unroll
        for (int p = 0; p < 2; ++p) {
            short8 s;
            #pragma unroll
            for (int e = 0; e < 8; ++e) s[e] = bf16_rne(acc[p*8+e]);
            *(short8*)(hp + p * 8) = s;
        }
    }
    const int wave = tid >> 6, lane = tid & 63, l16 = lane & 15, lq = lane >> 4;
    short8 bfrag[2][4];
    #pragma unroll
    for (int t = 0; t < 2; ++t) {
        const float* wp = W + (size_t)(wave * 32 + t * 16 + l16) * CIN;
        #pragma unroll
        for (int kb = 0; kb < 4; ++kb) {
            const float* wq = wp + kb * 32 + lq * 8;
            f32x4 f0 = *(const f32x4*)(wq);
            f32x4 f1 = *(const f32x4*)(wq + 4);
            short8 s;
            s[0]=bf16_rne(f0[0]); s[1]=bf16_rne(f0[1]); s[2]=bf16_rne(f0[2]); s[3]=bf16_rne(f0[3]);
            s[4]=bf16_rne(f1[0]); s[5]=bf16_rne(f1[1]); s[6]=bf16_rne(f1[2]); s[7]=bf16_rne(f1[3]);
            bfrag[t][kb] = s;
        }
    }
    const float bias0 = bias[wave * 32 + l16];
    const float bias1 = bias[wave * 32 + 16 + l16];
    __syncthreads();
    float* outb = out + (size_t)row0 * COUT;
    #pragma unroll
    for (int rt = 0; rt < MB1 / 16; ++rt) {
        const short* ap = h_s + (rt * 16 + l16) * HS_STRIDE + lq * 8;
        short8 afrag[4];
        #pragma unroll
        for (int kb = 0; kb < 4; ++kb) afrag[kb] = *(const short8*)(ap + kb * 32);
        #pragma unroll
        for (int t = 0; t < 2; ++t) {
            f32x4 acc = { 0.f, 0.f, 0.f, 0.f };
            #pragma unroll
            for (int kb = 0; kb < 4; ++kb)
                acc = __builtin_amdgcn_mfma_f32_16x16x32_bf16(afrag[kb], bfrag[t][kb], acc, 0, 0, 0);
            const float bv = t ? bias1 : bias0;
            const int col = wave * 32 + t * 16 + l16;
            #pragma unroll
            for (int ii = 0; ii < 4; ++ii) {
                const int row = rt * 16 + lq * 4 + ii;
                float v = acc[ii] + bv;
                outb[(size_t)row * COUT + col] = v > 0.f ? v : 0.f;
            }
        }
    }
}

extern "C" void kernel_launch(void* const* d_in, const int* in_sizes, int n_in,
                              void* d_out, int out_size, void* d_ws, size_t ws_size,
                              hipStream_t stream) {
    const float* x    = (const float*)d_in[0];
    const int*   eidx = (const int*)d_in[1];
    const float* W    = (const float*)d_in[2];
    const float* bias = (const float*)d_in[3];
    const float* eps  = (const float*)d_in[4];
    float*       out  = (float*)d_out;

    const size_t need = (size_t)XELEM * sizeof(ushort);  // 8 MiB (y in bf16)

    if (ws_size >= need) {
        ushort* yb = (ushort*)d_ws;
        gemm_xw  <<<dim3((BATCH * NNODE) / MB1), dim3(THREADS), 0, stream>>>(x, W, yb);
        gin_gather<<<dim3((BATCH * NNODE) / MB2), dim3(THREADS), 0, stream>>>(yb, eidx, bias, eps, out);
    } else {
        gin_fallback<<<dim3((BATCH * NNODE) / MB1), dim3(THREADS), 0, stream>>>(x, eidx, W, bias, eps, out);
    }
}